// Round 1
// baseline (298.749 us; speedup 1.0000x reference)
//
#include <hip/hip_runtime.h>
#include <stdint.h>

#define NROWS 100000
#define SDIM 150
#define HDIM 150
#define KSEG 160      // per-segment K, padded 150->160
#define NKB 20        // K-steps of 32 (total K = 640)
#define NCOL 640      // 4 gates * 160 padded cols
#define BM 64
#define NTHREADS 512
#define BSLICE 40960  // bytes per K-step slice of packed W (640 cols * 32 k * 2B)

using half8  = __attribute__((ext_vector_type(8))) _Float16;
using half2v = __attribute__((ext_vector_type(2))) _Float16;
using floatx4 = __attribute__((ext_vector_type(4))) float;

__device__ __forceinline__ float fsig(float x) {
  return __builtin_amdgcn_rcpf(1.0f + __expf(-x));
}
__device__ __forceinline__ float ftanh(float x) {
  return 2.0f * __builtin_amdgcn_rcpf(1.0f + __expf(-2.0f * x)) - 1.0f;
}

__device__ __forceinline__ void gload_lds16(const void* g, void* l) {
  __builtin_amdgcn_global_load_lds(
      (const __attribute__((address_space(1))) void*)g,
      (__attribute__((address_space(3))) void*)l, 16, 0, 0);
}

// Pack W = [w_in; w_out; u_in; u_out] (600x600 fp32) into f16, K-blocked,
// XOR-swizzled layout: element (col,k) at byte
//   kb*BSLICE + col*64 + slot*16 + (k&7)*2,  kb=k>>5, slot=((k>>3)&3)^((col>>1)&3)
// Zero-padded: per-segment k 150..159 = 0, per-gate col 150..159 = 0.
__global__ void pack_w_kernel(const float* __restrict__ w_in,
                              const float* __restrict__ w_out,
                              const float* __restrict__ u_in,
                              const float* __restrict__ u_out,
                              _Float16* __restrict__ wblk) {
  int idx = blockIdx.x * 256 + threadIdx.x;
  if (idx >= NKB * NCOL * 32) return;
  int j    = idx & 7;
  int slot = (idx >> 3) & 3;
  int col  = (idx >> 5) % NCOL;
  int kb   = idx / (NCOL * 32);
  int kg   = slot ^ ((col >> 1) & 3);   // XOR involution: recover k-group
  int k    = kb * 32 + kg * 8 + j;
  int seg  = k / KSEG;                  // 0..3: s_in, s_out, h_in, h_out weights
  int kl   = k - seg * KSEG;
  int g    = col / KSEG;
  int h    = col - g * KSEG;
  float v = 0.0f;
  if (kl < SDIM && h < HDIM) {
    const float* src = (seg == 0) ? w_in : (seg == 1) ? w_out
                     : (seg == 2) ? u_in : u_out;
    v = src[(g * SDIM + kl) * HDIM + h];
  }
  wblk[idx] = (_Float16)v;
}

// Fused GEMM + gates + elementwise. 64 rows/block, 8 waves:
// wave = (rgrp 0..1, gate 0..3); per wave 32 rows x 160 cols, acc[2][10] f32x4.
__global__ __launch_bounds__(NTHREADS) void lstm_fused_kernel(
    const float* __restrict__ s_in, const float* __restrict__ s_out,
    const float* __restrict__ h_in, const float* __restrict__ h_out,
    const float* __restrict__ last_c, const float* __restrict__ bias,
    const _Float16* __restrict__ wblk,
    float* __restrict__ out_hid, float* __restrict__ out_cell) {
  __shared__ __align__(16) char lds[4096 + BSLICE];
  char* ldsA = lds;          // 64 rows * 64B (32 f16, swizzled)
  char* ldsB = lds + 4096;   // 640 cols * 64B (swizzled); epilogue overlay

  const int tid  = threadIdx.x;
  const int lane = tid & 63;
  const int l15  = lane & 15;
  const int kgrp = lane >> 4;
  const int wid  = tid >> 6;
  const int rgrp = wid >> 2;
  const int gate = wid & 3;
  const int row0 = blockIdx.x * BM;

  const float* segp[4] = {s_in, s_out, h_in, h_out};

  // bias fragment: indexed by output column (C/D col = lane&15)
  float bfrag[10];
#pragma unroll
  for (int ct = 0; ct < 10; ++ct) {
    int h = ct * 16 + l15;
    bfrag[ct] = (h < HDIM) ? bias[gate * HDIM + h] : 0.0f;
  }

  floatx4 acc[2][10] = {};

  // A-staging assignment: thread -> (row, 4-float k-chunk)
  const int a_row = tid >> 3;
  const int a_kc  = tid & 7;
  const long n_a  = (long)row0 + a_row;
  const int a_slot = ((a_kc >> 1) ^ (a_row >> 1)) & 3;
  char* a_dst = ldsA + a_row * 64 + a_slot * 16 + (a_kc & 1) * 8;

  for (int kb = 0; kb < NKB; ++kb) {
    const int seg = kb / 5;
    const int kls = (kb % 5) * 32 + a_kc * 4;  // k within segment (pad >=150 -> 0)
    float v0 = 0.f, v1 = 0.f, v2 = 0.f, v3 = 0.f;
    if (n_a < NROWS) {
      const float* p = segp[seg] + n_a * SDIM + kls;
      if (kls + 3 < SDIM) {
        float2 q0 = *(const float2*)p;
        float2 q1 = *(const float2*)(p + 2);
        v0 = q0.x; v1 = q0.y; v2 = q1.x; v3 = q1.y;
      } else {
        if (kls + 0 < SDIM) v0 = p[0];
        if (kls + 1 < SDIM) v1 = p[1];
        if (kls + 2 < SDIM) v2 = p[2];
      }
    }
    __syncthreads();  // previous compute done; LDS reusable
    {
      union { _Float16 h[4]; uint2 u; } pk;
      pk.h[0] = (_Float16)v0; pk.h[1] = (_Float16)v1;
      pk.h[2] = (_Float16)v2; pk.h[3] = (_Float16)v3;
      *(uint2*)a_dst = pk.u;
    }
    {
      const char* gsrc = (const char*)wblk + (size_t)kb * BSLICE + tid * 16;
#pragma unroll
      for (int it = 0; it < 5; ++it)
        gload_lds16(gsrc + it * 8192, ldsB + tid * 16 + it * 8192);
    }
    __syncthreads();  // staging visible (compiler drains vmcnt/lgkmcnt)

    // A fragments: m = lane&15, k = 8*(lane>>4)+i (contiguous-8 layout)
    half8 af0, af1;
    {
      int r0 = rgrp * 32 + l15;
      int s0 = (kgrp ^ (r0 >> 1)) & 3;
      af0 = *(const half8*)(ldsA + r0 * 64 + s0 * 16);
      int r1 = r0 + 16;
      int s1 = (kgrp ^ (r1 >> 1)) & 3;
      af1 = *(const half8*)(ldsA + r1 * 64 + s1 * 16);
    }
#pragma unroll
    for (int ct = 0; ct < 10; ++ct) {
      int col = gate * 160 + ct * 16 + l15;
      int sl = (kgrp ^ (col >> 1)) & 3;
      half8 bf = *(const half8*)(ldsB + col * 64 + sl * 16);
      acc[0][ct] = __builtin_amdgcn_mfma_f32_16x16x32_f16(af0, bf, acc[0][ct], 0, 0, 0);
      acc[1][ct] = __builtin_amdgcn_mfma_f32_16x16x32_f16(af1, bf, acc[1][ct], 0, 0, 0);
    }
  }

  // Epilogue: two 32-row halves; gates exchanged via f16 LDS overlay on ldsB.
  _Float16* epi = (_Float16*)ldsB;
  for (int hr = 0; hr < 2; ++hr) {
    __syncthreads();  // prior LDS readers done
    if (rgrp == hr) {
#pragma unroll
      for (int mt = 0; mt < 2; ++mt) {
#pragma unroll
        for (int ct = 0; ct < 10; ++ct) {
          int colb = gate * 160 + ct * 16 + l15;
#pragma unroll
          for (int i = 0; i < 4; ++i) {
            // C/D layout: col = lane&15, row = (lane>>4)*4 + i  (m89-verified)
            int rl = mt * 16 + kgrp * 4 + i;
            float gv = fsig(acc[mt][ct][i] + bfrag[ct]);
            epi[rl * NCOL + colb] = (_Float16)gv;
          }
        }
      }
    }
    __syncthreads();
    // consume: gates[0]=input, [1]=output, [2]=forget, [3]=update
    for (int idx = tid; idx < 32 * 75; idx += NTHREADS) {
      int row = idx / 75;
      int h2  = idx - row * 75;
      long n = (long)row0 + hr * 32 + row;
      if (n < NROWS) {
        int h = h2 * 2;
        const _Float16* er = epi + row * NCOL + h;
        half2v gi = *(const half2v*)(er + 0 * 160);
        half2v go = *(const half2v*)(er + 1 * 160);
        half2v gf = *(const half2v*)(er + 2 * 160);
        half2v gu = *(const half2v*)(er + 3 * 160);
        float2 lc = *(const float2*)(last_c + n * HDIM + h);
        float c0 = (float)gf[0] * lc.x + (float)gu[0] * (float)gi[0];
        float c1 = (float)gf[1] * lc.y + (float)gu[1] * (float)gi[1];
        float hd0 = (float)go[0] * ftanh(c0);
        float hd1 = (float)go[1] * ftanh(c1);
        *(float2*)(out_hid  + n * HDIM + h) = make_float2(hd0, hd1);
        *(float2*)(out_cell + n * HDIM + h) = make_float2(c0, c1);
      }
    }
  }
}

extern "C" void kernel_launch(void* const* d_in, const int* in_sizes, int n_in,
                              void* d_out, int out_size, void* d_ws, size_t ws_size,
                              hipStream_t stream) {
  const float* s_in   = (const float*)d_in[0];
  const float* s_out  = (const float*)d_in[1];
  const float* h_in   = (const float*)d_in[2];
  const float* h_out  = (const float*)d_in[3];
  const float* last_c = (const float*)d_in[4];
  const float* w_in   = (const float*)d_in[5];
  const float* w_out  = (const float*)d_in[6];
  const float* u_in   = (const float*)d_in[7];
  const float* u_out  = (const float*)d_in[8];
  const float* b      = (const float*)d_in[9];

  _Float16* wblk = (_Float16*)d_ws;  // needs 819200 B

  pack_w_kernel<<<(NKB * NCOL * 32 + 255) / 256, 256, 0, stream>>>(
      w_in, w_out, u_in, u_out, wblk);

  float* out_hid  = (float*)d_out;
  float* out_cell = out_hid + (size_t)NROWS * HDIM;

  lstm_fused_kernel<<<(NROWS + BM - 1) / BM, NTHREADS, 0, stream>>>(
      s_in, s_out, h_in, h_out, last_c, b, wblk, out_hid, out_cell);
}

// Round 2
// 243.054 us; speedup vs baseline: 1.2291x; 1.2291x over previous
//
#include <hip/hip_runtime.h>
#include <stdint.h>

#define NROWS 100000
#define SDIM 150
#define HDIM 150
#define KSEG 160      // per-segment K, padded 150->160
#define NKB 20        // K-steps of 32 (total K = 640)
#define NCOL 640      // 4 gates * 160 padded cols
#define BM 128
#define NTHREADS 1024
#define BSLICE 40960  // bytes per K-step slice of packed W (640 cols * 32 k * 2B)
#define EPI_STRIDE 648  // f16 elements; 1296B, staggers banks across rows

using half8  = __attribute__((ext_vector_type(8))) _Float16;
using half2v = __attribute__((ext_vector_type(2))) _Float16;
using floatx4 = __attribute__((ext_vector_type(4))) float;

__device__ __forceinline__ float fsig(float x) {
  return __builtin_amdgcn_rcpf(1.0f + __expf(-x));
}
__device__ __forceinline__ float ftanh(float x) {
  return 2.0f * __builtin_amdgcn_rcpf(1.0f + __expf(-2.0f * x)) - 1.0f;
}

__device__ __forceinline__ void gload_lds16(const void* g, void* l) {
  __builtin_amdgcn_global_load_lds(
      (const __attribute__((address_space(1))) void*)g,
      (__attribute__((address_space(3))) void*)l, 16, 0, 0);
}

// Pack W = [w_in; w_out; u_in; u_out] (600x600 fp32) into f16, K-blocked,
// XOR-swizzled layout: element (col,k) at byte
//   kb*BSLICE + col*64 + slot*16 + (k&7)*2,  kb=k>>5, slot=((k>>3)&3)^((col>>1)&3)
__global__ void pack_w_kernel(const float* __restrict__ w_in,
                              const float* __restrict__ w_out,
                              const float* __restrict__ u_in,
                              const float* __restrict__ u_out,
                              _Float16* __restrict__ wblk) {
  int idx = blockIdx.x * 256 + threadIdx.x;
  if (idx >= NKB * NCOL * 32) return;
  int j    = idx & 7;
  int slot = (idx >> 3) & 3;
  int col  = (idx >> 5) % NCOL;
  int kb   = idx / (NCOL * 32);
  int kg   = slot ^ ((col >> 1) & 3);
  int k    = kb * 32 + kg * 8 + j;
  int seg  = k / KSEG;
  int kl   = k - seg * KSEG;
  int g    = col / KSEG;
  int h    = col - g * KSEG;
  float v = 0.0f;
  if (kl < SDIM && h < HDIM) {
    const float* src = (seg == 0) ? w_in : (seg == 1) ? w_out
                     : (seg == 2) ? u_in : u_out;
    v = src[(g * SDIM + kl) * HDIM + h];
  }
  wblk[idx] = (_Float16)v;
}

// Fused GEMM + gates + elementwise. 128 rows/block, 16 waves:
// wave = (rgrp 0..3, gate 0..3); per wave 32 rows x 160 cols, acc[2][10] f32x4.
// 2-phase double-buffered pipeline: stage(t+1) issued before compute(t),
// single __syncthreads per K-step drains loads issued one phase earlier.
__global__ __launch_bounds__(NTHREADS) void lstm_fused_kernel(
    const float* __restrict__ s_in, const float* __restrict__ s_out,
    const float* __restrict__ h_in, const float* __restrict__ h_out,
    const float* __restrict__ last_c, const float* __restrict__ bias,
    const _Float16* __restrict__ wblk,
    float* __restrict__ out_hid, float* __restrict__ out_cell) {
  // [0,8K) A0 | [8K,16K) A1 | [16K,56K+16K=57344) B0 | [57344,98304) B1
  __shared__ __align__(16) char lds[98304];

  const int tid  = threadIdx.x;
  const int lane = tid & 63;
  const int l15  = lane & 15;
  const int kgrp = lane >> 4;
  const int wid  = tid >> 6;
  const int rgrp = wid >> 2;   // 0..3
  const int gate = wid & 3;    // 0..3
  const int row0 = blockIdx.x * BM;

  const float* segp[4] = {s_in, s_out, h_in, h_out};

  // bias fragment (C/D col = lane&15)
  float bfrag[10];
#pragma unroll
  for (int ct = 0; ct < 10; ++ct) {
    int h = ct * 16 + l15;
    bfrag[ct] = (h < HDIM) ? bias[gate * HDIM + h] : 0.0f;
  }

  floatx4 acc[2][10] = {};

  // A-staging assignment: thread -> (row 0..127, 4-float k-chunk 0..7)
  const int a_row = tid >> 3;
  const int a_kc  = tid & 7;
  const long n_a  = (long)row0 + a_row;
  const int a_slot = ((a_kc >> 1) ^ (a_row >> 1)) & 3;
  const int a_off = a_row * 64 + a_slot * 16 + (a_kc & 1) * 8;

  // ---- helpers as lambdas (inlined) ----
  auto loadA = [&](int kb, float& v0, float& v1, float& v2, float& v3) {
    v0 = v1 = v2 = v3 = 0.f;
    const int seg = kb / 5;
    const int kls = (kb % 5) * 32 + a_kc * 4;
    if (n_a < NROWS && kls < SDIM) {
      const float* p = segp[seg] + (size_t)n_a * SDIM + kls;
      if (kls + 3 < SDIM) {
        float2 q0 = *(const float2*)p;
        float2 q1 = *(const float2*)(p + 2);
        v0 = q0.x; v1 = q0.y; v2 = q1.x; v3 = q1.y;
      } else {
        v0 = p[0];
        if (kls + 1 < SDIM) v1 = p[1];
      }
    }
  };
  auto stageB = [&](int kb, int buf) {
    const char* gsrc = (const char*)wblk + (size_t)kb * BSLICE;
    char* bdst = lds + 16384 + buf * BSLICE;
    gload_lds16(gsrc + tid * 16, bdst + tid * 16);
    gload_lds16(gsrc + (tid + 1024) * 16, bdst + (tid + 1024) * 16);
    if (tid < 512)
      gload_lds16(gsrc + (tid + 2048) * 16, bdst + (tid + 2048) * 16);
  };
  auto writeA = [&](int buf, float v0, float v1, float v2, float v3) {
    union { _Float16 h[4]; uint2 u; } pk;
    pk.h[0] = (_Float16)v0; pk.h[1] = (_Float16)v1;
    pk.h[2] = (_Float16)v2; pk.h[3] = (_Float16)v3;
    *(uint2*)(lds + buf * 8192 + a_off) = pk.u;
  };

  // ---- prologue: stage tile 0 into buffer 0 ----
  {
    float v0, v1, v2, v3;
    loadA(0, v0, v1, v2, v3);
    stageB(0, 0);
    writeA(0, v0, v1, v2, v3);
  }
  __syncthreads();

  int cur = 0;
  for (int kb = 0; kb < NKB; ++kb) {
    const int nkb = kb + 1;
    float v0, v1, v2, v3;
    if (nkb < NKB) {
      loadA(nkb, v0, v1, v2, v3);   // global->reg, latency hides under MFMA
      stageB(nkb, cur ^ 1);         // global->LDS async, drained at barrier
    }

    const char* aB = lds + cur * 8192;
    const char* bB = lds + 16384 + cur * BSLICE;
    half8 af0, af1;
    {
      int r0 = rgrp * 32 + l15;
      int s0 = (kgrp ^ (r0 >> 1)) & 3;
      af0 = *(const half8*)(aB + r0 * 64 + s0 * 16);
      int r1 = r0 + 16;
      int s1 = (kgrp ^ (r1 >> 1)) & 3;
      af1 = *(const half8*)(aB + r1 * 64 + s1 * 16);
    }
#pragma unroll
    for (int ct = 0; ct < 10; ++ct) {
      int col = gate * 160 + ct * 16 + l15;
      int sl = (kgrp ^ (col >> 1)) & 3;
      half8 bf = *(const half8*)(bB + col * 64 + sl * 16);
      acc[0][ct] = __builtin_amdgcn_mfma_f32_16x16x32_f16(af0, bf, acc[0][ct], 0, 0, 0);
      acc[1][ct] = __builtin_amdgcn_mfma_f32_16x16x32_f16(af1, bf, acc[1][ct], 0, 0, 0);
    }

    if (nkb < NKB) writeA(cur ^ 1, v0, v1, v2, v3);
    __syncthreads();
    cur ^= 1;
  }

  // ---- epilogue: two 64-row slices; gates exchanged via f16 LDS overlay ----
  _Float16* epi = (_Float16*)lds;  // 64 * EPI_STRIDE * 2B = 82944 <= 98304
  for (int hh = 0; hh < 2; ++hh) {
    if (hh) __syncthreads();  // consume of previous slice done
    if ((rgrp >> 1) == hh) {
      const int rbase = (rgrp & 1) * 32;
#pragma unroll
      for (int mt = 0; mt < 2; ++mt) {
#pragma unroll
        for (int ct = 0; ct < 10; ++ct) {
          int colb = gate * 160 + ct * 16 + l15;
#pragma unroll
          for (int i = 0; i < 4; ++i) {
            // C/D layout: col = lane&15, row = (lane>>4)*4 + i
            int rl = rbase + mt * 16 + kgrp * 4 + i;
            float gv = fsig(acc[mt][ct][i] + bfrag[ct]);
            epi[rl * EPI_STRIDE + colb] = (_Float16)gv;
          }
        }
      }
    }
    __syncthreads();
    // consume: gates[0]=input, [1]=output, [2]=forget, [3]=update
#pragma unroll
    for (int it = 0; it < 5; ++it) {
      int idx = tid + it * NTHREADS;
      if (idx < 64 * 75) {
        int row = idx / 75;
        int h2  = idx - row * 75;
        long n = (long)row0 + hh * 64 + row;
        if (n < NROWS) {
          int h = h2 * 2;
          const _Float16* er = epi + row * EPI_STRIDE + h;
          half2v gi = *(const half2v*)(er + 0 * 160);
          half2v go = *(const half2v*)(er + 1 * 160);
          half2v gf = *(const half2v*)(er + 2 * 160);
          half2v gu = *(const half2v*)(er + 3 * 160);
          float2 lc = *(const float2*)(last_c + n * HDIM + h);
          float c0 = (float)gf[0] * lc.x + (float)gu[0] * (float)gi[0];
          float c1 = (float)gf[1] * lc.y + (float)gu[1] * (float)gi[1];
          float hd0 = (float)go[0] * ftanh(c0);
          float hd1 = (float)go[1] * ftanh(c1);
          *(float2*)(out_hid  + n * HDIM + h) = make_float2(hd0, hd1);
          *(float2*)(out_cell + n * HDIM + h) = make_float2(c0, c1);
        }
      }
    }
  }
}

extern "C" void kernel_launch(void* const* d_in, const int* in_sizes, int n_in,
                              void* d_out, int out_size, void* d_ws, size_t ws_size,
                              hipStream_t stream) {
  const float* s_in   = (const float*)d_in[0];
  const float* s_out  = (const float*)d_in[1];
  const float* h_in   = (const float*)d_in[2];
  const float* h_out  = (const float*)d_in[3];
  const float* last_c = (const float*)d_in[4];
  const float* w_in   = (const float*)d_in[5];
  const float* w_out  = (const float*)d_in[6];
  const float* u_in   = (const float*)d_in[7];
  const float* u_out  = (const float*)d_in[8];
  const float* b      = (const float*)d_in[9];

  _Float16* wblk = (_Float16*)d_ws;  // needs 819200 B

  pack_w_kernel<<<(NKB * NCOL * 32 + 255) / 256, 256, 0, stream>>>(
      w_in, w_out, u_in, u_out, wblk);

  float* out_hid  = (float*)d_out;
  float* out_cell = out_hid + (size_t)NROWS * HDIM;

  lstm_fused_kernel<<<(NROWS + BM - 1) / BM, NTHREADS, 0, stream>>>(
      s_in, s_out, h_in, h_out, last_c, b, wblk, out_hid, out_cell);
}